// Round 1
// 334.082 us; speedup vs baseline: 1.0912x; 1.0912x over previous
//
#include <hip/hip_runtime.h>

// out[e] = concat(node_states[src[e]], node_states[tgt[e]])
// v2: 8 edges per wave, batched independent loads for MLP.
//
// Per wave (64 lanes): lanes 0-31 cover the source half of a row, lanes
// 32-63 the target half; each lane moves one float4 (16 B) per edge.
// A wave now owns 8 consecutive edges:
//   - 8 independent index loads issued together (one latency, not eight)
//   - 8 independent gather loads issued together
//   - 8 nontemporal stores (keeps the 328 MB output stream from thrashing
//     the caches that hold the 5 MB node_states table)
//
// Index dtype handling: reference emits int64 indices (values < 10000 so the
// high words are all 0). Instead of a branchy 64-bit load, probe once and
// read the little-endian LOW word with a uniform stride (2 words if int64,
// 1 if int32). No divergence, no 64-bit ops.

typedef float v4f __attribute__((ext_vector_type(4)));

#define EPW 8  // edges per wave

__global__ __launch_bounds__(256) void NodePropagator_75110388073048_kernel(
    const v4f* __restrict__ ns,       // node_states as [N, 32] v4f
    const int* __restrict__ src32,    // edge_sources (int32 word view)
    const int* __restrict__ tgt32,    // edge_targets (int32 word view)
    v4f* __restrict__ out,            // [E, 64] v4f
    int nEdges)
{
    int tid  = blockIdx.x * blockDim.x + threadIdx.x;
    int wid  = tid >> 6;              // global wave id
    int lane = tid & 63;
    int half = lane >> 5;             // 0 = source half, 1 = target half
    int c    = lane & 31;             // v4f chunk within the half

    int e0 = wid * EPW;               // first edge this wave owns
    if (e0 >= nEdges) return;

    // --- index dtype probe (int64 vs int32), uniform, cached loads ---
    // For genuine int32 data, 4 random values in [0,10000) all being 0 has
    // probability ~1e-16.
    bool is_i64 = (src32[1] == 0) & (src32[3] == 0) &
                  (src32[5] == 0) & (src32[7] == 0);
    int stride = is_i64 ? 2 : 1;      // int32 words per index element

    const int* idxp = half ? tgt32 : src32;

    // Batch 1: independent index loads (low word of each index).
    int rows[EPW];
#pragma unroll
    for (int k = 0; k < EPW; ++k) {
        int e  = e0 + k;
        int ec = e < nEdges ? e : nEdges - 1;   // clamp, store is guarded below
        rows[k] = idxp[ec * stride];
    }

    // Batch 2: independent gather loads (32 lanes x 16 B = 512 B contiguous
    // per half, per edge).
    v4f v[EPW];
#pragma unroll
    for (int k = 0; k < EPW; ++k)
        v[k] = ns[rows[k] * 32 + c];

    // Batch 3: nontemporal streaming stores (wave writes 1 KB contiguous
    // per edge).
#pragma unroll
    for (int k = 0; k < EPW; ++k) {
        int e = e0 + k;
        if (e < nEdges)
            __builtin_nontemporal_store(v[k], &out[e * 64 + lane]);
    }
}

extern "C" void kernel_launch(void* const* d_in, const int* in_sizes, int n_in,
                              void* d_out, int out_size, void* d_ws, size_t ws_size,
                              hipStream_t stream) {
    const v4f* ns  = (const v4f*)d_in[0];
    const int* src = (const int*)d_in[1];
    const int* tgt = (const int*)d_in[2];
    v4f*       out = (v4f*)d_out;

    int nEdges = in_sizes[1];                          // 320000
    long long waves  = ((long long)nEdges + EPW - 1) / EPW;
    long long threads = waves * 64;
    int block = 256;
    int grid  = (int)((threads + block - 1) / block);  // 10000 for E=320000

    NodePropagator_75110388073048_kernel<<<grid, block, 0, stream>>>(
        ns, src, tgt, out, nEdges);
}